// Round 4
// baseline (425.326 us; speedup 1.0000x reference)
//
#include <hip/hip_runtime.h>

typedef __attribute__((ext_vector_type(4))) float f32x4;
typedef __attribute__((ext_vector_type(8))) short short8x;

#define DIM   4096
#define NB    8
#define NN    2048
#define NROWS (NB*NN)
#define NHD   8
#define NQ    7
#define NHQ   56
#define SCALE 0.04419417382415922f  /* 1/sqrt(512) */

// ---- workspace layout (float offsets), ~41 MB total
#define OFF_MU     0L          /* 16384 */
#define OFF_RSTD   16384L      /* 16384 */
#define OFF_Q7     32768L      /* 7*4096 = 28672 */
#define OFF_A      61440L      /* 64 */
#define OFF_D0     61504L      /* 64 */
#define OFF_S1     61568L      /* 64 */
#define OFF_SMST   61632L      /* 448 float2 = 896 */
#define OFF_CTXM   62528L      /* 8*4096 */
#define OFF_GFIN   95296L      /* 8*4096 */
#define OFF_YM     128064L     /* 64*4096 = 262144 */
#define OFF_UGBF   390208L     /* 64*4096 ushorts = 131072 floats */
#define OFF_STATP  521280L     /* 4*16384 float2 = 131072 */
#define OFF_SCT    652352L     /* 56(+pad) rows x 16384 -> 64*16384 = 1048576 */
#define OFF_BIG    1700928L    /* time-shared:
          phase A: upart 4*56*4096 = 917504        (uproj->ured)
          phase B: raw   4*16384*64 = 4194304      (scores2->sepi)
          phase C: am 131072 @+0, part 32*64*4096=8388608 @+131072 */
#define OFF_AM     (OFF_BIG)
#define OFF_PART   (OFF_BIG + 131072L)

__device__ __forceinline__ unsigned short f2bf(float f) {   // RNE
  union { float f; unsigned int u; } v; v.f = f;
  return (unsigned short)((v.u + 0x7FFFu + ((v.u >> 16) & 1u)) >> 16);
}
__device__ __forceinline__ unsigned short f2bfr(float f) {  // cheap round
  union { float f; unsigned int u; } v; v.f = f;
  return (unsigned short)((v.u + 0x8000u) >> 16);
}

__device__ __forceinline__ float waveSum(float v) {
  #pragma unroll
  for (int m = 1; m < 64; m <<= 1) v += __shfl_xor(v, m);
  return v;
}
__device__ __forceinline__ float blockSum256(float v, float* red) {
  v = waveSum(v);
  __syncthreads();
  if ((threadIdx.x & 63) == 0) red[threadIdx.x >> 6] = v;
  __syncthreads();
  return red[0] + red[1] + red[2] + red[3];
}
__device__ __forceinline__ float blockMax256(float v, float* red) {
  #pragma unroll
  for (int m = 1; m < 64; m <<= 1) v = fmaxf(v, __shfl_xor(v, m));
  __syncthreads();
  if ((threadIdx.x & 63) == 0) red[threadIdx.x >> 6] = v;
  __syncthreads();
  return fmaxf(fmaxf(red[0], red[1]), fmaxf(red[2], red[3]));
}

// ---- P0a: q7 = clip(slots) @ Wq^T + bq  (one wave per d, float4, inline clip)
__global__ __launch_bounds__(256) void k_qproj(const float* __restrict__ ipw,
    const float* __restrict__ ipb, const float* __restrict__ slots, float* __restrict__ q7) {
  const int w = threadIdx.x >> 6, l = threadIdx.x & 63;
  const int d = blockIdx.x * 4 + w;
  const float4* wr4 = (const float4*)(ipw + (long)d * DIM);
  float acc[7] = {0,0,0,0,0,0,0};
  for (int e4 = l; e4 < 1024; e4 += 64) {
    float4 wv = wr4[e4];
    #pragma unroll
    for (int s = 0; s < 7; s++) {
      float4 sv = ((const float4*)(slots + (long)s*DIM))[e4];
      sv.x = fminf(fmaxf(sv.x, -10.f), 10.f); sv.y = fminf(fmaxf(sv.y, -10.f), 10.f);
      sv.z = fminf(fmaxf(sv.z, -10.f), 10.f); sv.w = fminf(fmaxf(sv.w, -10.f), 10.f);
      acc[s] += wv.x*sv.x + wv.y*sv.y + wv.z*sv.z + wv.w*sv.w;
    }
  }
  #pragma unroll
  for (int s = 0; s < 7; s++) acc[s] = waveSum(acc[s]);
  if (l == 0) {
    float bq = ipb[d];
    #pragma unroll
    for (int s = 0; s < 7; s++) q7[(long)s*DIM + d] = acc[s] + bq;
  }
}

// ---- P0b: init A=0, D0 = SCALE * sum_hd q*bk   (one wave per hq)
__global__ __launch_bounds__(64) void k_adinit(const float* __restrict__ q7,
    const float* __restrict__ ipb, float* __restrict__ Aarr, float* __restrict__ D0arr) {
  const int hq = blockIdx.x, h = hq / 7, q = hq % 7;
  float acc = 0;
  for (int i = threadIdx.x; i < 512; i += 64)
    acc += q7[(long)q*DIM + h*512 + i] * ipb[DIM + h*512 + i];
  acc = waveSum(acc);
  if (threadIdx.x == 0) { Aarr[hq] = 0.f; D0arr[hq] = SCALE * acc; }
}

// ---- P0c: partial u: upart[(c*8+h)*7+s][e] = sum_{hd in chunk c} q7*Wk
__global__ __launch_bounds__(256) void k_uproj(const float* __restrict__ ipw,
    const float* __restrict__ q7, float* __restrict__ upart) {
  const int h = blockIdx.y, c = blockIdx.z;
  const int e = blockIdx.x * 256 + threadIdx.x;
  __shared__ float qs[7][128];
  for (int i = threadIdx.x; i < 7*128; i += 256) {
    int s = i >> 7, hd = i & 127;
    qs[s][hd] = q7[(long)s*DIM + h*512 + c*128 + hd];
  }
  __syncthreads();
  float acc[7] = {0,0,0,0,0,0,0};
  const float* wp = ipw + ((long)(DIM + h*512 + c*128))*DIM + e;
  for (int hd = 0; hd < 128; hd++) {
    float wv = wp[(long)hd * DIM];
    #pragma unroll
    for (int s = 0; s < 7; s++) acc[s] += qs[s][hd] * wv;
  }
  #pragma unroll
  for (int s = 0; s < 7; s++) upart[(long)((c*8 + h)*7 + s)*DIM + e] = acc[s];
}

// ---- P0d: u = scale*sum_c upart; ugbf = bf16(u*ln_g); atomics A += u*g, D0 += u*lnb
__global__ __launch_bounds__(256) void k_ured(const float* __restrict__ upart,
    const float* __restrict__ lng, const float* __restrict__ lnb,
    unsigned short* __restrict__ ugbf, float* __restrict__ Aarr, float* __restrict__ D0arr) {
  const int h = blockIdx.y;
  const int e = blockIdx.x * 256 + threadIdx.x;
  if (h == 8) {  // zero pad rows 56..63 (ws poisoned)
    #pragma unroll
    for (int r = 0; r < 8; r++) ugbf[(long)(56 + r)*DIM + e] = 0;
    return;
  }
  float ge = lng[e], be = lnb[e];
  #pragma unroll
  for (int s = 0; s < 7; s++) {
    float u = 0;
    #pragma unroll
    for (int c = 0; c < 4; c++) u += upart[(long)((c*8 + h)*7 + s)*DIM + e];
    u *= SCALE;
    ugbf[(long)(h*7 + s)*DIM + e] = f2bf(u * ge);
    float pa = waveSum(u * ge);
    float pd = waveSum(u * be);
    if ((threadIdx.x & 63) == 0) {
      atomicAdd(&Aarr[h*7 + s], pa);
      atomicAdd(&D0arr[h*7 + s], pd);
    }
  }
}

// ---- P1: barrier-free raw scores + LN-stat partials. K split 4-way.
__global__ __launch_bounds__(256) void k_scores2(const float* __restrict__ x,
    const unsigned short* __restrict__ ugbf, float* __restrict__ raw, float2* __restrict__ statp) {
  const int tid = threadIdx.x;
  const int w = tid >> 6, l = tid & 63;
  const int lr = l & 15, lk8 = (l >> 4) * 8;
  const int rowblk = blockIdx.x >> 2, ks = blockIdx.x & 3;
  const int row0w = rowblk * 64 + w * 16;
  const long arow = (long)(row0w + lr) * DIM;
  const int kbase = ks * 1024;
  f32x4 acc0 = {0,0,0,0}, acc1 = {0,0,0,0}, acc2 = {0,0,0,0}, acc3 = {0,0,0,0};
  float sx = 0.f, sxx = 0.f;
  const long b0 = (long)(0*16 + lr)*DIM, b1 = (long)(1*16 + lr)*DIM,
             b2 = (long)(2*16 + lr)*DIM, b3 = (long)(3*16 + lr)*DIM;
  #pragma unroll 2
  for (int kc = kbase; kc < kbase + 1024; kc += 32) {
    const float4 v0 = *(const float4*)(x + arow + kc + lk8);
    const float4 v1 = *(const float4*)(x + arow + kc + lk8 + 4);
    sx  += (v0.x + v0.y) + (v0.z + v0.w) + (v1.x + v1.y) + (v1.z + v1.w);
    sxx += v0.x*v0.x + v0.y*v0.y + v0.z*v0.z + v0.w*v0.w
         + v1.x*v1.x + v1.y*v1.y + v1.z*v1.z + v1.w*v1.w;
    short8x a;
    a[0] = (short)f2bfr(v0.x); a[1] = (short)f2bfr(v0.y);
    a[2] = (short)f2bfr(v0.z); a[3] = (short)f2bfr(v0.w);
    a[4] = (short)f2bfr(v1.x); a[5] = (short)f2bfr(v1.y);
    a[6] = (short)f2bfr(v1.z); a[7] = (short)f2bfr(v1.w);
    short8x bb0 = *(const short8x*)(ugbf + b0 + kc + lk8);
    acc0 = __builtin_amdgcn_mfma_f32_16x16x32_bf16(a, bb0, acc0, 0, 0, 0);
    short8x bb1 = *(const short8x*)(ugbf + b1 + kc + lk8);
    acc1 = __builtin_amdgcn_mfma_f32_16x16x32_bf16(a, bb1, acc1, 0, 0, 0);
    short8x bb2 = *(const short8x*)(ugbf + b2 + kc + lk8);
    acc2 = __builtin_amdgcn_mfma_f32_16x16x32_bf16(a, bb2, acc2, 0, 0, 0);
    short8x bb3 = *(const short8x*)(ugbf + b3 + kc + lk8);
    acc3 = __builtin_amdgcn_mfma_f32_16x16x32_bf16(a, bb3, acc3, 0, 0, 0);
  }
  sx += __shfl_xor(sx, 16);  sx += __shfl_xor(sx, 32);
  sxx += __shfl_xor(sxx, 16); sxx += __shfl_xor(sxx, 32);
  if (l < 16) {
    float2 p; p.x = sx; p.y = sxx;
    statp[(long)ks*NROWS + row0w + l] = p;
  }
  const long base = ((long)ks*NROWS + row0w) * 64;
  #pragma unroll
  for (int i = 0; i < 4; i++) {
    long ro = base + (long)((l >> 4)*4 + i) * 64 + lr;
    raw[ro +  0] = acc0[i];
    raw[ro + 16] = acc1[i];
    raw[ro + 32] = acc2[i];
    raw[ro + 48] = acc3[i];
  }
}

// ---- P1b: combine K-split partials, finalize LN, write transposed scores
__global__ __launch_bounds__(256) void k_sepi(const float* __restrict__ raw,
    const float2* __restrict__ statp, const float* __restrict__ Aarr,
    const float* __restrict__ D0arr, float* __restrict__ mu_o, float* __restrict__ rstd_o,
    float* __restrict__ sct) {
  const int w = threadIdx.x >> 6, l = threadIdx.x & 63;
  const int row = blockIdx.x * 4 + w;
  float s = 0;
  #pragma unroll
  for (int ks = 0; ks < 4; ks++) s += raw[((long)ks*NROWS + row)*64 + l];
  float sx = 0, sxx = 0;
  #pragma unroll
  for (int ks = 0; ks < 4; ks++) {
    float2 p = statp[(long)ks*NROWS + row];
    sx += p.x; sxx += p.y;
  }
  float mu = sx * (1.0f/DIM), var = sxx * (1.0f/DIM) - mu*mu;
  float rs = rsqrtf(var + 1e-5f);
  if (l == 0) { mu_o[row] = mu; rstd_o[row] = rs; }
  if (l < NHQ) sct[(long)l*NROWS + row] = rs*(s - mu*Aarr[l]) + D0arr[l];
}

// ---- P2a: per-(b,hq) softmax stats {max, 1/sum}; block 0 zeroes s1
__global__ __launch_bounds__(256) void k_smax(const float* __restrict__ sct,
    float2* __restrict__ stats, float* __restrict__ s1) {
  __shared__ float red[4];
  if (blockIdx.x == 0 && threadIdx.x < 64) s1[threadIdx.x] = 0.f;
  const int b = blockIdx.x / NHQ, hq = blockIdx.x % NHQ;
  const int tid = threadIdx.x;
  const float* sp = sct + (long)hq*NROWS + (long)b*NN;
  float s[8]; float mx = -3.4e38f;
  #pragma unroll
  for (int j = 0; j < 8; j++) { s[j] = sp[tid + j*256]; mx = fmaxf(mx, s[j]); }
  mx = blockMax256(mx, red);
  float sum = 0;
  #pragma unroll
  for (int j = 0; j < 8; j++) sum += __expf(s[j] - mx);
  sum = blockSum256(sum, red);
  if (tid == 0) { float2 o; o.x = mx; o.y = 1.0f/sum; stats[b*NHQ + hq] = o; }
}

// ---- P2b: recompute p; emit am, out_attn, s1 (wave atomics). grid 64 (b*8+nc)
__global__ __launch_bounds__(256) void k_attnmeans(const float* __restrict__ sct,
    const float2* __restrict__ stats, const float* __restrict__ mu, const float* __restrict__ rstd,
    float* __restrict__ am, float* __restrict__ s1, float* __restrict__ out_attn) {
  const int b = blockIdx.x >> 3, nc = blockIdx.x & 7;
  const int tid = threadIdx.x;
  const int n = nc*256 + tid, row = b*NN + n;
  __shared__ float2 st[56];
  if (tid < 56) st[tid] = stats[b*NHQ + tid];
  __syncthreads();
  const float mur = mu[row] * rstd[row];
  float aq[7] = {0,0,0,0,0,0,0};
  #pragma unroll
  for (int h = 0; h < 8; h++) {
    float ah = 0;
    #pragma unroll
    for (int q = 0; q < 7; q++) {
      float2 s2 = st[h*7 + q];
      float p = __expf(sct[(long)(h*7 + q)*NROWS + row] - s2.x) * s2.y;
      aq[q] += p; ah += p;
    }
    float amv = ah * (1.0f/7.0f);
    am[((long)(b*8 + h))*NN + n] = amv;
    float sv = waveSum(amv * mur);
    if ((tid & 63) == 0) atomicAdd(&s1[b*8 + h], sv);
  }
  #pragma unroll
  for (int q = 0; q < 7; q++) out_attn[((long)(b*NQ + q))*NN + n] = aq[q] * 0.125f;
}

// ---- P3: partial y over 32 n-chunks of 64 rows. grid 1024: b(8) x ec(4) x nc(32)
__global__ __launch_bounds__(256) void k_ypart(const float* __restrict__ x,
    const float* __restrict__ am, const float* __restrict__ rstd, float* __restrict__ part) {
  const int bid = blockIdx.x;
  const int b = bid >> 7, ec = (bid >> 5) & 3, nc = bid & 31;
  __shared__ float amr[8][64];
  const int tid = threadIdx.x;
  for (int i = tid; i < 512; i += 256) {
    int h = i >> 6, nn = i & 63;
    int row = b*NN + nc*64 + nn;
    amr[h][nn] = am[((long)(b*8 + h))*NN + nc*64 + nn] * rstd[row];
  }
  __syncthreads();
  const int e = ec*1024 + tid*4;
  float ax[8], ay[8], az[8], aw[8];
  #pragma unroll
  for (int h = 0; h < 8; h++) { ax[h]=0; ay[h]=0; az[h]=0; aw[h]=0; }
  const float* xp = x + ((long)(b*NN + nc*64))*DIM + e;
  #pragma unroll 2
  for (int nn = 0; nn < 64; nn++) {
    const float4 xv = *(const float4*)(xp + (long)nn*DIM);
    #pragma unroll
    for (int h = 0; h < 8; h++) {
      float a = amr[h][nn];
      ax[h] += a*xv.x; ay[h] += a*xv.y; az[h] += a*xv.z; aw[h] += a*xv.w;
    }
  }
  #pragma unroll
  for (int h = 0; h < 8; h++) {
    float4 o; o.x = ax[h]; o.y = ay[h]; o.z = az[h]; o.w = aw[h];
    *(float4*)&part[((long)(nc*64 + b*8 + h))*DIM + e] = o;
  }
}

// ---- P3b: reduce 32 partials; fuse ym = ln_g*(y - s1) + ln_b
__global__ __launch_bounds__(256) void k_yred(const float* __restrict__ part,
    const float* __restrict__ s1, const float* __restrict__ lng, const float* __restrict__ lnb,
    float* __restrict__ ym) {
  const long i4 = (long)blockIdx.x*256 + threadIdx.x; // 65536 float4s
  const float4* p4 = (const float4*)part;
  float4 s = p4[i4];
  #pragma unroll
  for (int nc = 1; nc < 32; nc++) {
    float4 v = p4[(long)nc*65536 + i4];
    s.x += v.x; s.y += v.y; s.z += v.z; s.w += v.w;
  }
  const int bh = (int)(i4 >> 10), e4 = (int)(i4 & 1023);
  float sv = s1[bh];
  float4 g = ((const float4*)lng)[e4], bb = ((const float4*)lnb)[e4];
  float4 o;
  o.x = g.x*(s.x - sv) + bb.x; o.y = g.y*(s.y - sv) + bb.y;
  o.z = g.z*(s.z - sv) + bb.z; o.w = g.w*(s.w - sv) + bb.w;
  ((float4*)ym)[i4] = o;
}

// ---- P4a: ctxm[b][d] = Wv_row(d) . ym[b, d>>9, :] + bv[d]
__global__ __launch_bounds__(256) void k_ctxm(const float* __restrict__ ipw,
    const float* __restrict__ ipb, const float* __restrict__ ym, float* __restrict__ ctxm) {
  const int w = threadIdx.x >> 6, l = threadIdx.x & 63;
  const int d = blockIdx.x*4 + w;
  const int h = d >> 9;
  const float4* wr4 = (const float4*)(ipw + ((long)(2*DIM + d))*DIM);
  float acc[8] = {0,0,0,0,0,0,0,0};
  for (int e4 = l; e4 < 1024; e4 += 64) {
    float4 wv = wr4[e4];
    #pragma unroll
    for (int b = 0; b < 8; b++) {
      float4 y = ((const float4*)(ym + (long)(b*8 + h)*DIM))[e4];
      acc[b] += wv.x*y.x + wv.y*y.y + wv.z*y.z + wv.w*y.w;
    }
  }
  #pragma unroll
  for (int b = 0; b < 8; b++) acc[b] = waveSum(acc[b]);
  if (l == 0) {
    float bias = ipb[2*DIM + d];
    #pragma unroll
    for (int b = 0; b < 8; b++) ctxm[(long)b*DIM + d] = acc[b] + bias;
  }
}

// ---- P4b: gfin[b][d] = tanh(alpha) * (sm[d] + opw_row(d).ctxm[b] + opb[d]), sm inline
__global__ __launch_bounds__(256) void k_gvec(const float* __restrict__ opw,
    const float* __restrict__ opb, const float* __restrict__ ctxm, const float* __restrict__ slots,
    const float* __restrict__ alpha, float* __restrict__ gfin) {
  const int w = threadIdx.x >> 6, l = threadIdx.x & 63;
  const int d = blockIdx.x*4 + w;
  const float4* wr4 = (const float4*)(opw + (long)d*DIM);
  float acc[8] = {0,0,0,0,0,0,0,0};
  for (int e4 = l; e4 < 1024; e4 += 64) {
    float4 wv = wr4[e4];
    #pragma unroll
    for (int b = 0; b < 8; b++) {
      float4 c = ((const float4*)(ctxm + (long)b*DIM))[e4];
      acc[b] += wv.x*c.x + wv.y*c.y + wv.z*c.z + wv.w*c.w;
    }
  }
  #pragma unroll
  for (int b = 0; b < 8; b++) acc[b] = waveSum(acc[b]);
  if (l == 0) {
    float smv = 0;
    #pragma unroll
    for (int q = 0; q < 7; q++)
      smv += fminf(fmaxf(slots[(long)q*DIM + d], -10.f), 10.f);
    smv *= (1.0f/7.0f);
    float t = tanhf(alpha[0]);
    float base = smv + opb[d];
    #pragma unroll
    for (int b = 0; b < 8; b++) gfin[(long)b*DIM + d] = t * (base + acc[b]);
  }
}

// ---- P5: x_refined = x + g[b]
__global__ __launch_bounds__(256) void k_refine(const float* __restrict__ x,
    const float* __restrict__ gfin, float* __restrict__ out) {
  const float4* x4 = (const float4*)x;
  const float4* g4 = (const float4*)gfin;
  float4* o4 = (float4*)out;
  const long total = (long)NROWS * 1024;
  for (long i4 = (long)blockIdx.x*256 + threadIdx.x; i4 < total; i4 += (long)gridDim.x*256) {
    long b = i4 >> 21;
    long e4 = i4 & 1023;
    float4 xv = x4[i4], gv = g4[b*1024 + e4];
    float4 o; o.x = xv.x + gv.x; o.y = xv.y + gv.y; o.z = xv.z + gv.z; o.w = xv.w + gv.w;
    o4[i4] = o;
  }
}

extern "C" void kernel_launch(void* const* d_in, const int* in_sizes, int n_in,
                              void* d_out, int out_size, void* d_ws, size_t ws_size,
                              hipStream_t stream) {
  const float* x     = (const float*)d_in[0];
  const float* slots = (const float*)d_in[1];
  const float* lng   = (const float*)d_in[2];
  const float* lnb   = (const float*)d_in[3];
  const float* ipw   = (const float*)d_in[4];
  const float* ipb   = (const float*)d_in[5];
  const float* opw   = (const float*)d_in[6];
  const float* opb   = (const float*)d_in[7];
  const float* alpha = (const float*)d_in[8];
  float* out = (float*)d_out;
  float* ws  = (float*)d_ws;

  float* mu     = ws + OFF_MU;
  float* rstd   = ws + OFF_RSTD;
  float* q7     = ws + OFF_Q7;
  float* Aarr   = ws + OFF_A;
  float* D0arr  = ws + OFF_D0;
  float* s1     = ws + OFF_S1;
  float2* stats = (float2*)(ws + OFF_SMST);
  float* ctxm   = ws + OFF_CTXM;
  float* gfin   = ws + OFF_GFIN;
  float* ym     = ws + OFF_YM;
  unsigned short* ugbf = (unsigned short*)(ws + OFF_UGBF);
  float2* statp = (float2*)(ws + OFF_STATP);
  float* sct    = ws + OFF_SCT;
  float* upart  = ws + OFF_BIG;
  float* raw    = ws + OFF_BIG;
  float* am     = ws + OFF_AM;
  float* part   = ws + OFF_PART;
  float* out_attn = out + (long)NROWS * DIM;

  hipLaunchKernelGGL(k_qproj,     dim3(1024),      dim3(256), 0, stream, ipw, ipb, slots, q7);
  hipLaunchKernelGGL(k_adinit,    dim3(56),        dim3(64),  0, stream, q7, ipb, Aarr, D0arr);
  hipLaunchKernelGGL(k_uproj,     dim3(16, 8, 4),  dim3(256), 0, stream, ipw, q7, upart);
  hipLaunchKernelGGL(k_ured,      dim3(16, 9),     dim3(256), 0, stream, upart, lng, lnb, ugbf, Aarr, D0arr);
  hipLaunchKernelGGL(k_scores2,   dim3(1024),      dim3(256), 0, stream, x, ugbf, raw, statp);
  hipLaunchKernelGGL(k_sepi,      dim3(4096),      dim3(256), 0, stream, raw, statp, Aarr, D0arr, mu, rstd, sct);
  hipLaunchKernelGGL(k_smax,      dim3(448),       dim3(256), 0, stream, sct, stats, s1);
  hipLaunchKernelGGL(k_attnmeans, dim3(64),        dim3(256), 0, stream, sct, stats, mu, rstd, am, s1, out_attn);
  hipLaunchKernelGGL(k_ypart,     dim3(1024),      dim3(256), 0, stream, x, am, rstd, part);
  hipLaunchKernelGGL(k_yred,      dim3(256),       dim3(256), 0, stream, part, s1, lng, lnb, ym);
  hipLaunchKernelGGL(k_ctxm,      dim3(1024),      dim3(256), 0, stream, ipw, ipb, ym, ctxm);
  hipLaunchKernelGGL(k_gvec,      dim3(1024),      dim3(256), 0, stream, opw, opb, ctxm, slots, alpha, gfin);
  hipLaunchKernelGGL(k_refine,    dim3(8192),      dim3(256), 0, stream, x, gfin, out);
}